// Round 6
// baseline (222.891 us; speedup 1.0000x reference)
//
#include <hip/hip_runtime.h>

#define B_    64
#define HW_   196
#define HWP_  224
#define D_    768
#define E_    256
#define C_    10
#define MP_   (B_*HWP_)   // 14336 padded rows
#define K3K_  (E_*D_)     // 196608 deep-K for final contraction
#define K3NB_ 192         // K-split blocks for k3

typedef _Float16 half8 __attribute__((ext_vector_type(8)));
typedef _Float16 half4 __attribute__((ext_vector_type(4)));
typedef float    f32x4 __attribute__((ext_vector_type(4)));

// ---- kT: fp32 x -> fp16 transposed xt [B][D][HWP] (hi only; k2's B operand) ----
// half2-combine trick: phase1 builds transposed tile with vector b32 LDS writes
// (pitch 66 -> ~2-way banks, free), phase2 reads 4x b32 + one 16B global store.
__global__ __launch_bounds__(256) void kT(const float* __restrict__ x,
                                          _Float16* __restrict__ xt) {
  __shared__ _Float16 tht[64 * 66];
  const int bid = blockIdx.x;
  const int b = bid / 48, rem = bid % 48;
  const int hpt = rem / 12, dt = rem % 12;
  int hp0 = hpt * 64; if (hpt == 3) hp0 = 160;   // overlap tiles idempotent
  const int d0 = dt * 64;
  const int t = threadIdx.x;
#pragma unroll
  for (int i = 0; i < 2; i++) {
    int s = t + 256 * i;
    int hpp = s >> 4;          // 0..31
    int dq = s & 15;
    int hp = hp0 + 2 * hpp;
    const float* src = &x[((size_t)b * HW_ + hp) * D_ + d0 + 4 * dq];
    float4 v0 = (hp < HW_)     ? *(const float4*)src         : make_float4(0.f, 0.f, 0.f, 0.f);
    float4 v1 = (hp + 1 < HW_) ? *(const float4*)(src + D_)  : make_float4(0.f, 0.f, 0.f, 0.f);
    float a0[4] = {v0.x, v0.y, v0.z, v0.w};
    float a1[4] = {v1.x, v1.y, v1.z, v1.w};
#pragma unroll
    for (int j = 0; j < 4; j++) {
      union { _Float16 h[2]; unsigned u; } p;
      p.h[0] = (_Float16)a0[j];
      p.h[1] = (_Float16)a1[j];
      *(unsigned*)&tht[(4 * dq + j) * 66 + 2 * hpp] = p.u;
    }
  }
  __syncthreads();
#pragma unroll
  for (int i = 0; i < 2; i++) {
    int s = t + 256 * i;
    int dl = s >> 3;           // 0..63
    int c = s & 7;
    union { _Float16 h[8]; uint4 v; unsigned u[4]; } r;
#pragma unroll
    for (int uu = 0; uu < 4; uu++)
      r.u[uu] = *(const unsigned*)&tht[dl * 66 + c * 8 + uu * 2];
    *(uint4*)&xt[((size_t)b * D_ + d0 + dl) * HWP_ + hp0 + c * 8] = r.v;
  }
}

// ---------------- K1: sign GEMM, fp32 inputs, fp16 hi/lo split built in-staging ----
// Block 128 threads (2 waves), tile 128m x 64n, wave-tile 64x64 (4x4 frags x3 terms:
// 16 ds_read_b128 per 48 MFMA -> MFMA-bound). Grid 112x4 = 448 blocks.
__global__ __launch_bounds__(128) void k1_signs(const float* __restrict__ x,
                                                const float* __restrict__ agw,
                                                const float* __restrict__ bias,
                                                _Float16* __restrict__ st) {
  __shared__ _Float16 Ah[128 * 40];   // stride 40: R2-measured ~6% conflict, b128-aligned
  __shared__ _Float16 Al[128 * 40];
  __shared__ _Float16 Bh[64 * 40];
  __shared__ _Float16 Bl[64 * 40];
  const int m0 = blockIdx.x * 128;
  const int n0 = blockIdx.y * 64;
  const int tid = threadIdx.x;        // 0..127
  const int wave = tid >> 6, lane = tid & 63;
  const int q = lane >> 4, l15 = lane & 15;
  const int wm = wave * 64;
  const int r0 = tid >> 3;            // 0..15
  const int cq = (tid & 7) * 4;       // 0..28

  // hoist A/B row pointers (k-independent)
  const float* ap[8]; bool av[8];
#pragma unroll
  for (int i = 0; i < 8; i++) {
    int r = r0 + 16 * i;              // 0..127
    int m = m0 + r;
    int b = m / HWP_, hp = m - b * HWP_;
    av[i] = (hp < HW_);
    ap[i] = &x[((size_t)b * HW_ + (hp < HW_ ? hp : 0)) * D_ + cq];
  }
  const float* bp[4];
#pragma unroll
  for (int i = 0; i < 4; i++) bp[i] = &agw[(size_t)(n0 + r0 + 16 * i) * D_ + cq];

  f32x4 acc[4][4] = {};

  for (int k0 = 0; k0 < D_; k0 += 32) {
    __syncthreads();
#pragma unroll
    for (int i = 0; i < 8; i++) {
      int r = r0 + 16 * i;
      float4 v = av[i] ? *(const float4*)(ap[i] + k0) : make_float4(0.f, 0.f, 0.f, 0.f);
      float vv[4] = {v.x, v.y, v.z, v.w};
      half4 h, l;
#pragma unroll
      for (int j = 0; j < 4; j++) {
        _Float16 hj = (_Float16)vv[j];
        h[j] = hj;
        l[j] = (_Float16)(vv[j] - (float)hj);
      }
      *(half4*)&Ah[r * 40 + cq] = h;
      *(half4*)&Al[r * 40 + cq] = l;
    }
#pragma unroll
    for (int i = 0; i < 4; i++) {
      int r = r0 + 16 * i;            // 0..63
      float4 v = *(const float4*)(bp[i] + k0);
      float vv[4] = {v.x, v.y, v.z, v.w};
      half4 h, l;
#pragma unroll
      for (int j = 0; j < 4; j++) {
        _Float16 hj = (_Float16)vv[j];
        h[j] = hj;
        l[j] = (_Float16)(vv[j] - (float)hj);
      }
      *(half4*)&Bh[r * 40 + cq] = h;
      *(half4*)&Bl[r * 40 + cq] = l;
    }
    __syncthreads();
    half8 af[4], alf[4], bfh[4], bfl[4];
#pragma unroll
    for (int t = 0; t < 4; t++) {
      af[t]  = *(const half8*)&Ah[(wm + t * 16 + l15) * 40 + q * 8];
      alf[t] = *(const half8*)&Al[(wm + t * 16 + l15) * 40 + q * 8];
      bfh[t] = *(const half8*)&Bh[(t * 16 + l15) * 40 + q * 8];
      bfl[t] = *(const half8*)&Bl[(t * 16 + l15) * 40 + q * 8];
    }
#pragma unroll
    for (int mt = 0; mt < 4; mt++)
#pragma unroll
      for (int nt = 0; nt < 4; nt++) {
        acc[mt][nt] = __builtin_amdgcn_mfma_f32_16x16x32_f16(af[mt],  bfh[nt], acc[mt][nt], 0, 0, 0);
        acc[mt][nt] = __builtin_amdgcn_mfma_f32_16x16x32_f16(alf[mt], bfh[nt], acc[mt][nt], 0, 0, 0);
        acc[mt][nt] = __builtin_amdgcn_mfma_f32_16x16x32_f16(af[mt],  bfl[nt], acc[mt][nt], 0, 0, 0);
      }
  }
  // epilogue: +bias, sign, transposed store ST[b][e][hp] (pads hp>=196 get 0)
#pragma unroll
  for (int mt = 0; mt < 4; mt++)
#pragma unroll
    for (int nt = 0; nt < 4; nt++) {
      int e = n0 + nt * 16 + l15;
      float bv = bias[e];
#pragma unroll
      for (int r = 0; r < 4; r++) {
        int m = m0 + wm + mt * 16 + q * 4 + r;   // C/D: row=quad*4+reg, col=lane&15
        int b = m / HWP_;
        int hp = m - b * HWP_;
        float v = acc[mt][nt][r] + bv;
        _Float16 s = (hp < HW_ && v > 0.0f) ? (_Float16)1.0f : (_Float16)0.0f;
        st[((size_t)b * E_ + e) * HWP_ + hp] = s;
      }
    }
}

// ---------------- K2: per-batch G = S^T · X, both operands row-major in K=hp ----------
__global__ __launch_bounds__(256) void k2_g(const _Float16* __restrict__ st,
                                            const _Float16* __restrict__ xt,
                                            _Float16* __restrict__ g) {
  __shared__ _Float16 As[128 * 40];
  __shared__ _Float16 Bs[128 * 40];
  const int b  = blockIdx.y;
  const int e0 = (blockIdx.x / 6) * 128;
  const int d0 = (blockIdx.x % 6) * 128;
  const int tid = threadIdx.x;
  const int wave = tid >> 6, lane = tid & 63;
  const int wm = (wave & 1) * 64, wn = (wave >> 1) * 64;
  const int q = lane >> 4, l15 = lane & 15;
  const int sr = tid >> 2, sk = (tid & 3) * 8;
  f32x4 acc[4][4] = {};

  const _Float16* arow = &st[((size_t)b * E_ + e0) * HWP_];
  const _Float16* brow = &xt[((size_t)b * D_ + d0) * HWP_];

  for (int k0 = 0; k0 < HWP_; k0 += 32) {
    __syncthreads();
    *(half8*)&As[sr * 40 + sk]        = *(const half8*)&arow[(size_t)sr * HWP_ + k0 + sk];
    *(half8*)&As[(sr + 64) * 40 + sk] = *(const half8*)&arow[(size_t)(sr + 64) * HWP_ + k0 + sk];
    *(half8*)&Bs[sr * 40 + sk]        = *(const half8*)&brow[(size_t)sr * HWP_ + k0 + sk];
    *(half8*)&Bs[(sr + 64) * 40 + sk] = *(const half8*)&brow[(size_t)(sr + 64) * HWP_ + k0 + sk];
    __syncthreads();
    half8 af[4], bfr[4];
#pragma unroll
    for (int t = 0; t < 4; t++) {
      af[t]  = *(const half8*)&As[(wm + t * 16 + l15) * 40 + q * 8];
      bfr[t] = *(const half8*)&Bs[(wn + t * 16 + l15) * 40 + q * 8];
    }
#pragma unroll
    for (int mt = 0; mt < 4; mt++)
#pragma unroll
      for (int nt = 0; nt < 4; nt++)
        acc[mt][nt] = __builtin_amdgcn_mfma_f32_16x16x32_f16(af[mt], bfr[nt], acc[mt][nt], 0, 0, 0);
  }
#pragma unroll
  for (int mt = 0; mt < 4; mt++)
#pragma unroll
    for (int nt = 0; nt < 4; nt++) {
      int d = d0 + wn + nt * 16 + l15;
#pragma unroll
      for (int r = 0; r < 4; r++) {
        int e = e0 + wm + mt * 16 + q * 4 + r;
        g[((size_t)b * E_ + e) * D_ + d] = (_Float16)acc[mt][nt][r];
      }
    }
}

// ---------------- K2b: permute lm_w -> W2[c][e*768+d] fp16, c padded to 16 ----------------
__global__ __launch_bounds__(192) void k2b_w2(const float* __restrict__ lmw,
                                              _Float16* __restrict__ w2) {
  const int e = blockIdx.x, c = blockIdx.y, t = threadIdx.x;
  _Float16* dst = &w2[(size_t)c * K3K_ + (size_t)e * D_ + t * 4];
  half4 o;
  if (c < C_) {
    float4 v = *(const float4*)&lmw[((size_t)e * C_ + c) * D_ + t * 4];
    o[0] = (_Float16)v.x; o[1] = (_Float16)v.y; o[2] = (_Float16)v.z; o[3] = (_Float16)v.w;
  } else {
    o[0] = o[1] = o[2] = o[3] = (_Float16)0.0f;
  }
  *(half4*)dst = o;
}

// ---------------- K3: preds = G_flat(64 x 196608) · W2^T, deep-K split MFMA ----------------
__global__ __launch_bounds__(256) void k3_mfma(const _Float16* __restrict__ g,
                                               const _Float16* __restrict__ w2,
                                               float* __restrict__ out) {
  __shared__ float sp[B_ * C_];
  const int tid = threadIdx.x;
  const int wave = tid >> 6, lane = tid & 63;
  const int q = lane >> 4, l15 = lane & 15;
  const int kbase = blockIdx.x * (K3K_ / K3NB_) + wave * 256;
  f32x4 acc[4] = {};

  for (int i = tid; i < B_ * C_; i += 256) sp[i] = 0.0f;

#pragma unroll
  for (int ks = 0; ks < 8; ks++) {
    int k = kbase + ks * 32 + q * 8;
    half8 bfrag = *(const half8*)&w2[(size_t)l15 * K3K_ + k];
#pragma unroll
    for (int mt = 0; mt < 4; mt++) {
      half8 afrag = *(const half8*)&g[(size_t)(mt * 16 + l15) * K3K_ + k];
      acc[mt] = __builtin_amdgcn_mfma_f32_16x16x32_f16(afrag, bfrag, acc[mt], 0, 0, 0);
    }
  }
  __syncthreads();
  int c = l15;
  if (c < C_) {
#pragma unroll
    for (int mt = 0; mt < 4; mt++)
#pragma unroll
      for (int r = 0; r < 4; r++) {
        int b = mt * 16 + q * 4 + r;
        atomicAdd(&sp[b * C_ + c], acc[mt][r]);
      }
  }
  __syncthreads();
  const float scale = 1.0f / (196.0f * 256.0f);
  for (int i = tid; i < B_ * C_; i += 256) atomicAdd(&out[i], sp[i] * scale);
}

extern "C" void kernel_launch(void* const* d_in, const int* in_sizes, int n_in,
                              void* d_out, int out_size, void* d_ws, size_t ws_size,
                              hipStream_t stream) {
  const float* x    = (const float*)d_in[0];   // (64,196,768)
  const float* ag_w = (const float*)d_in[1];   // (256,768)
  const float* ag_b = (const float*)d_in[2];   // (256,)
  const float* lm_w = (const float*)d_in[3];   // (2560,768)
  float* out = (float*)d_out;                  // (64,10)

  char* ws = (char*)d_ws;
  _Float16* xt = (_Float16*)(ws + 0);          // 22,020,096 B
  _Float16* st = (_Float16*)(ws + 22020096);   //  7,340,032 B
  _Float16* w2 = (_Float16*)(ws + 29360128);   //  6,291,456 B
  _Float16* gb = (_Float16*)(ws + 35651584);   // 25,165,824 B -> total ~60.8 MB

  hipMemsetAsync(d_out, 0, (size_t)out_size * sizeof(float), stream);

  kT<<<dim3(B_ * 4 * 12), dim3(256), 0, stream>>>(x, xt);
  k2b_w2<<<dim3(E_, 16), dim3(192), 0, stream>>>(lm_w, w2);
  k1_signs<<<dim3(MP_ / 128, E_ / 64), dim3(128), 0, stream>>>(x, ag_w, ag_b, st);
  k2_g<<<dim3(12, B_), dim3(256), 0, stream>>>(st, xt, gb);
  k3_mfma<<<dim3(K3NB_), dim3(256), 0, stream>>>(gb, w2, out);
}

// Round 7
// 200.302 us; speedup vs baseline: 1.1128x; 1.1128x over previous
//
#include <hip/hip_runtime.h>

#define B_    64
#define HW_   196
#define HWP_  224
#define D_    768
#define E_    256
#define C_    10
#define MP_   (B_*HWP_)   // 14336 padded rows
#define K3K_  (E_*D_)     // 196608 deep-K for final contraction
#define K3NB_ 384         // K-split blocks for k3 (512 k each, 4 waves x 128)

typedef _Float16 half8 __attribute__((ext_vector_type(8)));
typedef _Float16 half4 __attribute__((ext_vector_type(4)));
typedef float    f32x4 __attribute__((ext_vector_type(4)));

// ---- kT: fp32 x -> fp16 transposed xt [B][D][HWP] (k2's B operand) ----
__global__ __launch_bounds__(256) void kT(const float* __restrict__ x,
                                          _Float16* __restrict__ xt) {
  __shared__ _Float16 tht[64 * 66];
  const int bid = blockIdx.x;
  const int b = bid / 48, rem = bid % 48;
  const int hpt = rem / 12, dt = rem % 12;
  int hp0 = hpt * 64; if (hpt == 3) hp0 = 160;   // overlap tiles idempotent
  const int d0 = dt * 64;
  const int t = threadIdx.x;
#pragma unroll
  for (int i = 0; i < 2; i++) {
    int s = t + 256 * i;
    int hpp = s >> 4;          // 0..31
    int dq = s & 15;
    int hp = hp0 + 2 * hpp;
    const float* src = &x[((size_t)b * HW_ + hp) * D_ + d0 + 4 * dq];
    float4 v0 = (hp < HW_)     ? *(const float4*)src         : make_float4(0.f, 0.f, 0.f, 0.f);
    float4 v1 = (hp + 1 < HW_) ? *(const float4*)(src + D_)  : make_float4(0.f, 0.f, 0.f, 0.f);
    float a0[4] = {v0.x, v0.y, v0.z, v0.w};
    float a1[4] = {v1.x, v1.y, v1.z, v1.w};
#pragma unroll
    for (int j = 0; j < 4; j++) {
      union { _Float16 h[2]; unsigned u; } p;
      p.h[0] = (_Float16)a0[j];
      p.h[1] = (_Float16)a1[j];
      *(unsigned*)&tht[(4 * dq + j) * 66 + 2 * hpp] = p.u;
    }
  }
  __syncthreads();
#pragma unroll
  for (int i = 0; i < 2; i++) {
    int s = t + 256 * i;
    int dl = s >> 3;           // 0..63
    int c = s & 7;
    union { _Float16 h[8]; uint4 v; unsigned u[4]; } r;
#pragma unroll
    for (int uu = 0; uu < 4; uu++)
      r.u[uu] = *(const unsigned*)&tht[dl * 66 + c * 8 + uu * 2];
    *(uint4*)&xt[((size_t)b * D_ + d0 + dl) * HWP_ + hp0 + c * 8] = r.v;
  }
}

// ---------------- K1: sign GEMM; fp32 sources, hi/lo split built during staging ----
// R5's proven 4-wave shape: 256 thr, tile 128m x 64n, wave 64x32, BK=32, grid 448.
// Only change vs R5: global reads are fp32 x/ag_w (kills k0_x/k0_w + 88MB round-trip).
__global__ __launch_bounds__(256) void k1_signs(const float* __restrict__ x,
                                                const float* __restrict__ agw,
                                                const float* __restrict__ bias,
                                                _Float16* __restrict__ st) {
  __shared__ _Float16 Ah[128 * 40];   // stride 40: proven low-conflict, b128-aligned
  __shared__ _Float16 Al[128 * 40];
  __shared__ _Float16 Bh[64 * 40];
  __shared__ _Float16 Bl[64 * 40];
  const int m0 = blockIdx.x * 128;
  const int n0 = blockIdx.y * 64;
  const int tid = threadIdx.x;
  const int wave = tid >> 6, lane = tid & 63;
  const int wm = (wave & 1) * 64, wn = (wave >> 1) * 32;
  const int q = lane >> 4, l15 = lane & 15;
  const int sr = tid >> 2;            // 0..63
  const int sc = (tid & 3) * 8;       // float offset 0..24

  // hoist row pointers + validity (k-independent)
  const float* xrow[2]; bool xval[2];
#pragma unroll
  for (int i = 0; i < 2; i++) {
    int m = m0 + sr + 64 * i;
    int b = m / HWP_, hp = m - b * HWP_;
    xval[i] = (hp < HW_);
    xrow[i] = &x[((size_t)b * HW_ + (hp < HW_ ? hp : 0)) * D_ + sc];
  }
  const float* wrow = &agw[(size_t)(n0 + sr) * D_ + sc];

  f32x4 acc[4][2] = {};

  for (int k0 = 0; k0 < D_; k0 += 32) {
    __syncthreads();
#pragma unroll
    for (int i = 0; i < 2; i++) {
      int r = sr + 64 * i;
      float4 v0 = xval[i] ? *(const float4*)(xrow[i] + k0)     : make_float4(0.f, 0.f, 0.f, 0.f);
      float4 v1 = xval[i] ? *(const float4*)(xrow[i] + k0 + 4) : make_float4(0.f, 0.f, 0.f, 0.f);
      float vv[8] = {v0.x, v0.y, v0.z, v0.w, v1.x, v1.y, v1.z, v1.w};
      half8 h, l;
#pragma unroll
      for (int j = 0; j < 8; j++) {
        _Float16 hj = (_Float16)vv[j];
        h[j] = hj;
        l[j] = (_Float16)(vv[j] - (float)hj);
      }
      *(half8*)&Ah[r * 40 + sc] = h;
      *(half8*)&Al[r * 40 + sc] = l;
    }
    {
      float4 v0 = *(const float4*)(wrow + k0);
      float4 v1 = *(const float4*)(wrow + k0 + 4);
      float vv[8] = {v0.x, v0.y, v0.z, v0.w, v1.x, v1.y, v1.z, v1.w};
      half8 h, l;
#pragma unroll
      for (int j = 0; j < 8; j++) {
        _Float16 hj = (_Float16)vv[j];
        h[j] = hj;
        l[j] = (_Float16)(vv[j] - (float)hj);
      }
      *(half8*)&Bh[sr * 40 + sc] = h;
      *(half8*)&Bl[sr * 40 + sc] = l;
    }
    __syncthreads();
    half8 af[4], alf[4], bfh[2], bfl[2];
#pragma unroll
    for (int t = 0; t < 4; t++) {
      af[t]  = *(const half8*)&Ah[(wm + t * 16 + l15) * 40 + q * 8];
      alf[t] = *(const half8*)&Al[(wm + t * 16 + l15) * 40 + q * 8];
    }
#pragma unroll
    for (int t = 0; t < 2; t++) {
      bfh[t] = *(const half8*)&Bh[(wn + t * 16 + l15) * 40 + q * 8];
      bfl[t] = *(const half8*)&Bl[(wn + t * 16 + l15) * 40 + q * 8];
    }
#pragma unroll
    for (int mt = 0; mt < 4; mt++)
#pragma unroll
      for (int nt = 0; nt < 2; nt++) {
        acc[mt][nt] = __builtin_amdgcn_mfma_f32_16x16x32_f16(af[mt],  bfh[nt], acc[mt][nt], 0, 0, 0);
        acc[mt][nt] = __builtin_amdgcn_mfma_f32_16x16x32_f16(alf[mt], bfh[nt], acc[mt][nt], 0, 0, 0);
        acc[mt][nt] = __builtin_amdgcn_mfma_f32_16x16x32_f16(af[mt],  bfl[nt], acc[mt][nt], 0, 0, 0);
      }
  }
  // epilogue: +bias, sign, transposed store ST[b][e][hp] (pads hp>=196 get 0)
#pragma unroll
  for (int mt = 0; mt < 4; mt++)
#pragma unroll
    for (int nt = 0; nt < 2; nt++) {
      int e = n0 + wn + nt * 16 + l15;
      float bv = bias[e];
#pragma unroll
      for (int r = 0; r < 4; r++) {
        int m = m0 + wm + mt * 16 + q * 4 + r;   // C/D: row=quad*4+reg, col=lane&15
        int b = m / HWP_;
        int hp = m - b * HWP_;
        float v = acc[mt][nt][r] + bv;
        _Float16 s = (hp < HW_ && v > 0.0f) ? (_Float16)1.0f : (_Float16)0.0f;
        st[((size_t)b * E_ + e) * HWP_ + hp] = s;
      }
    }
}

// ---------------- K2: per-batch G = S^T · X, both operands row-major in K=hp ----------
__global__ __launch_bounds__(256) void k2_g(const _Float16* __restrict__ st,
                                            const _Float16* __restrict__ xt,
                                            _Float16* __restrict__ g) {
  __shared__ _Float16 As[128 * 40];
  __shared__ _Float16 Bs[128 * 40];
  const int b  = blockIdx.y;
  const int e0 = (blockIdx.x / 6) * 128;
  const int d0 = (blockIdx.x % 6) * 128;
  const int tid = threadIdx.x;
  const int wave = tid >> 6, lane = tid & 63;
  const int wm = (wave & 1) * 64, wn = (wave >> 1) * 64;
  const int q = lane >> 4, l15 = lane & 15;
  const int sr = tid >> 2, sk = (tid & 3) * 8;
  f32x4 acc[4][4] = {};

  const _Float16* arow = &st[((size_t)b * E_ + e0) * HWP_];
  const _Float16* brow = &xt[((size_t)b * D_ + d0) * HWP_];

  for (int k0 = 0; k0 < HWP_; k0 += 32) {
    __syncthreads();
    *(half8*)&As[sr * 40 + sk]        = *(const half8*)&arow[(size_t)sr * HWP_ + k0 + sk];
    *(half8*)&As[(sr + 64) * 40 + sk] = *(const half8*)&arow[(size_t)(sr + 64) * HWP_ + k0 + sk];
    *(half8*)&Bs[sr * 40 + sk]        = *(const half8*)&brow[(size_t)sr * HWP_ + k0 + sk];
    *(half8*)&Bs[(sr + 64) * 40 + sk] = *(const half8*)&brow[(size_t)(sr + 64) * HWP_ + k0 + sk];
    __syncthreads();
    half8 af[4], bfr[4];
#pragma unroll
    for (int t = 0; t < 4; t++) {
      af[t]  = *(const half8*)&As[(wm + t * 16 + l15) * 40 + q * 8];
      bfr[t] = *(const half8*)&Bs[(wn + t * 16 + l15) * 40 + q * 8];
    }
#pragma unroll
    for (int mt = 0; mt < 4; mt++)
#pragma unroll
      for (int nt = 0; nt < 4; nt++)
        acc[mt][nt] = __builtin_amdgcn_mfma_f32_16x16x32_f16(af[mt], bfr[nt], acc[mt][nt], 0, 0, 0);
  }
#pragma unroll
  for (int mt = 0; mt < 4; mt++)
#pragma unroll
    for (int nt = 0; nt < 4; nt++) {
      int d = d0 + wn + nt * 16 + l15;
#pragma unroll
      for (int r = 0; r < 4; r++) {
        int e = e0 + wm + mt * 16 + q * 4 + r;
        g[((size_t)b * E_ + e) * D_ + d] = (_Float16)acc[mt][nt][r];
      }
    }
}

// ---------------- K2b: permute lm_w -> W2[c][e*768+d] fp16, c padded to 16 ----------------
__global__ __launch_bounds__(192) void k2b_w2(const float* __restrict__ lmw,
                                              _Float16* __restrict__ w2) {
  const int e = blockIdx.x, c = blockIdx.y, t = threadIdx.x;
  _Float16* dst = &w2[(size_t)c * K3K_ + (size_t)e * D_ + t * 4];
  half4 o;
  if (c < C_) {
    float4 v = *(const float4*)&lmw[((size_t)e * C_ + c) * D_ + t * 4];
    o[0] = (_Float16)v.x; o[1] = (_Float16)v.y; o[2] = (_Float16)v.z; o[3] = (_Float16)v.w;
  } else {
    o[0] = o[1] = o[2] = o[3] = (_Float16)0.0f;
  }
  *(half4*)dst = o;
}

// ---------------- K3: partial preds per K-block, no global atomics ----------------
// 384 blocks x 512 k (4 waves x 128). Block reduces into LDS sp[640], writes
// part[i*K3NB_+blk] (contiguous per-output for k3b).
__global__ __launch_bounds__(256) void k3_mfma(const _Float16* __restrict__ g,
                                               const _Float16* __restrict__ w2,
                                               float* __restrict__ part) {
  __shared__ float sp[B_ * C_];
  const int tid = threadIdx.x;
  const int wave = tid >> 6, lane = tid & 63;
  const int q = lane >> 4, l15 = lane & 15;
  const int blk = blockIdx.x;
  const int kbase = blk * (K3K_ / K3NB_) + wave * 128;
  f32x4 acc[4] = {};

  for (int i = tid; i < B_ * C_; i += 256) sp[i] = 0.0f;

#pragma unroll
  for (int ks = 0; ks < 4; ks++) {
    int k = kbase + ks * 32 + q * 8;
    half8 bfrag = *(const half8*)&w2[(size_t)l15 * K3K_ + k];
#pragma unroll
    for (int mt = 0; mt < 4; mt++) {
      half8 afrag = *(const half8*)&g[(size_t)(mt * 16 + l15) * K3K_ + k];
      acc[mt] = __builtin_amdgcn_mfma_f32_16x16x32_f16(afrag, bfrag, acc[mt], 0, 0, 0);
    }
  }
  __syncthreads();
  if (l15 < C_) {
#pragma unroll
    for (int mt = 0; mt < 4; mt++)
#pragma unroll
      for (int r = 0; r < 4; r++) {
        int b = mt * 16 + q * 4 + r;
        atomicAdd(&sp[b * C_ + l15], acc[mt][r]);
      }
  }
  __syncthreads();
  for (int i = tid; i < B_ * C_; i += 256) part[(size_t)i * K3NB_ + blk] = sp[i];
}

// ---------------- K3b: out[i] = scale * sum_j part[i][j] ----------------
__global__ __launch_bounds__(640) void k3b_red(const float* __restrict__ part,
                                               float* __restrict__ out) {
  const int i = threadIdx.x;
  const float* p = &part[(size_t)i * K3NB_];
  float s = 0.f;
#pragma unroll 4
  for (int j = 0; j < K3NB_; j += 4) {
    float4 v = *(const float4*)&p[j];
    s += v.x + v.y + v.z + v.w;
  }
  out[i] = s * (1.0f / (196.0f * 256.0f));
}

extern "C" void kernel_launch(void* const* d_in, const int* in_sizes, int n_in,
                              void* d_out, int out_size, void* d_ws, size_t ws_size,
                              hipStream_t stream) {
  const float* x    = (const float*)d_in[0];   // (64,196,768)
  const float* ag_w = (const float*)d_in[1];   // (256,768)
  const float* ag_b = (const float*)d_in[2];   // (256,)
  const float* lm_w = (const float*)d_in[3];   // (2560,768)
  float* out = (float*)d_out;                  // (64,10)

  char* ws = (char*)d_ws;
  _Float16* xt   = (_Float16*)(ws + 0);          // 22,020,096 B
  _Float16* st   = (_Float16*)(ws + 22020096);   //  7,340,032 B
  _Float16* w2   = (_Float16*)(ws + 29360128);   //  6,291,456 B
  _Float16* gb   = (_Float16*)(ws + 35651584);   // 25,165,824 B
  float*    part = (float*)   (ws + 60817408);   //    983,040 B -> total ~61.8 MB

  kT<<<dim3(B_ * 4 * 12), dim3(256), 0, stream>>>(x, xt);
  k2b_w2<<<dim3(E_, 16), dim3(192), 0, stream>>>(lm_w, w2);
  k1_signs<<<dim3(MP_ / 128, E_ / 64), dim3(256), 0, stream>>>(x, ag_w, ag_b, st);
  k2_g<<<dim3(12, B_), dim3(256), 0, stream>>>(st, xt, gb);
  k3_mfma<<<dim3(K3NB_), dim3(256), 0, stream>>>(gb, w2, part);
  k3b_red<<<dim3(1), dim3(640), 0, stream>>>(part, out);
}